// Round 1
// baseline (83.606 us; speedup 1.0000x reference)
//
#include <hip/hip_runtime.h>

#define HH 512
#define WW 512
#define NIMG 16
#define RAD 4
#define SEG 32          // output rows per thread
#define EPSF 1e-5f

// Each thread: one x-column, SEG output rows. Register ring of 9 horizontal
// sums per channel (I, J, I2, J2, IJ); shift-based so all indices are
// compile-time (no scratch). Zero padding handled by bounds checks.
__global__ __launch_bounds__(256) void ncc_main(const float* __restrict__ Iin,
                                                const float* __restrict__ Jin,
                                                double* __restrict__ acc) {
    const int tid = threadIdx.x;
    const int bid = blockIdx.x;
    const int xt  = bid & 1;          // 2 x-tiles of 256
    const int seg = (bid >> 1) & 15;  // 16 segments of 32 rows
    const int n   = bid >> 5;         // image index
    const int x   = xt * 256 + tid;
    const int y0  = seg * SEG;

    const float* Ib = Iin + (size_t)n * HH * WW;
    const float* Jb = Jin + (size_t)n * HH * WW;

    float hI[9], hJ[9], hI2[9], hJ2[9], hIJ[9];

    auto hrow = [&](int yy, float& sI, float& sJ, float& sI2, float& sJ2, float& sIJ) {
        sI = 0.f; sJ = 0.f; sI2 = 0.f; sJ2 = 0.f; sIJ = 0.f;
        if (yy >= 0 && yy < HH) {
            const float* rI = Ib + yy * WW;
            const float* rJ = Jb + yy * WW;
            #pragma unroll
            for (int dx = -RAD; dx <= RAD; ++dx) {
                int xx = x + dx;
                if (xx >= 0 && xx < WW) {
                    float a = rI[xx];
                    float b = rJ[xx];
                    sI += a;
                    sJ += b;
                    sI2 = fmaf(a, a, sI2);
                    sJ2 = fmaf(b, b, sJ2);
                    sIJ = fmaf(a, b, sIJ);
                }
            }
        }
    };

    // Warm-up: rows y0-4 .. y0+3 into slots 0..7
    #pragma unroll
    for (int s = 0; s < 8; ++s) {
        hrow(y0 - RAD + s, hI[s], hJ[s], hI2[s], hJ2[s], hIJ[s]);
    }

    float local = 0.f;
    for (int i = 0; i < SEG; ++i) {
        const int y = y0 + i;
        // new bottom row y+4 into slot 8
        hrow(y + RAD, hI[8], hJ[8], hI2[8], hJ2[8], hIJ[8]);

        float SI = 0.f, SJ = 0.f, SI2 = 0.f, SJ2 = 0.f, SIJ = 0.f;
        #pragma unroll
        for (int k = 0; k < 9; ++k) {
            SI += hI[k]; SJ += hJ[k]; SI2 += hI2[k]; SJ2 += hJ2[k]; SIJ += hIJ[k];
        }

        const float inv = 1.0f / 81.0f;
        const float uI = SI * inv;
        const float uJ = SJ * inv;
        const float cross = SIJ - uJ * SI - uI * SJ + uI * uJ * 81.0f;
        const float Ivar  = SI2 - 2.0f * uI * SI + uI * uI * 81.0f;
        const float Jvar  = SJ2 - 2.0f * uJ * SJ + uJ * uJ * 81.0f;
        const float cc = cross * cross / (Ivar * Jvar + EPSF);
        local += cc;

        // shift ring (all compile-time indices)
        #pragma unroll
        for (int k = 0; k < 8; ++k) {
            hI[k]  = hI[k + 1];
            hJ[k]  = hJ[k + 1];
            hI2[k] = hI2[k + 1];
            hJ2[k] = hJ2[k + 1];
            hIJ[k] = hIJ[k + 1];
        }
    }

    // wave (64-lane) reduction
    #pragma unroll
    for (int off = 32; off > 0; off >>= 1) {
        local += __shfl_down(local, off);
    }
    __shared__ float wsum[4];
    if ((tid & 63) == 0) wsum[tid >> 6] = local;
    __syncthreads();
    if (tid == 0) {
        float b = wsum[0] + wsum[1] + wsum[2] + wsum[3];
        atomicAdd(acc, (double)b);
    }
}

__global__ void ncc_final(const double* __restrict__ acc, float* __restrict__ out) {
    out[0] = 1.0f - (float)(acc[0] * (1.0 / (double)((size_t)NIMG * HH * WW)));
}

extern "C" void kernel_launch(void* const* d_in, const int* in_sizes, int n_in,
                              void* d_out, int out_size, void* d_ws, size_t ws_size,
                              hipStream_t stream) {
    const float* I = (const float*)d_in[0];
    const float* J = (const float*)d_in[1];
    float* out = (float*)d_out;
    double* acc = (double*)d_ws;

    hipMemsetAsync(acc, 0, sizeof(double), stream);
    // 16 images * 16 segments * 2 x-tiles = 512 blocks
    ncc_main<<<512, 256, 0, stream>>>(I, J, acc);
    ncc_final<<<1, 1, 0, stream>>>(acc, out);
}